// Round 1
// 2139.213 us; speedup vs baseline: 1.2023x; 1.2023x over previous
//
#include <hip/hip_runtime.h>

typedef __attribute__((ext_vector_type(8))) short bh8;
typedef __attribute__((ext_vector_type(4))) float f32x4;

#define NB   8
#define NLAY 3
#define LSEQ 2016
#define NH   4
#define DM   256
#define FCN  64
#define MR   (NB*LSEQ)     /* 16128 */
#define SCL  0.0625f       /* 1/sqrt(D)=1/16 per module quirk; folded into Q projection */
#define SP   2056          /* LDS S pitch (elements): 2048 data+pad cols, 16B-aligned rows */

__device__ __forceinline__ float b2f(unsigned short u) {
  union { unsigned int i; float f; } c; c.i = ((unsigned int)u) << 16; return c.f;
}
__device__ __forceinline__ unsigned short f2b(float f) {
  union { float f; unsigned int i; } c; c.f = f;
  unsigned int r = c.i + 0x7fffu + ((c.i >> 16) & 1u);  // RNE
  return (unsigned short)(r >> 16);
}
__device__ __forceinline__ unsigned int pk_bf16(float lo, float hi) {
  unsigned int r;
  asm("v_cvt_pk_bf16_f32 %0, %1, %2" : "=v"(r) : "v"(lo), "v"(hi));
  return r;
}

// ---------------- fp32 -> bf16 weight conversion ----------------
__global__ __launch_bounds__(256) void k_f2bf(const float* __restrict__ s,
    unsigned short* __restrict__ d, int n) {
  int i = blockIdx.x * 256 + threadIdx.x;
  if (i < n) d[i] = f2b(s[i]);
}

// ---------------- input embedding: h = x @ in_w + in_b (K=2) ----------------
__global__ __launch_bounds__(256) void k_embed(const float* __restrict__ x,
    const float* __restrict__ w, const float* __restrict__ bias,
    float* __restrict__ h, unsigned short* __restrict__ hb) {
  int m = blockIdx.x, d = threadIdx.x;
  float v = x[m*2] * w[d] + x[m*2+1] * w[DM + d] + bias[d];
  size_t idx = (size_t)m * DM + d;
  h[idx] = v;
  hb[idx] = f2b(v);
}

// ---------------- generic bf16 MFMA GEMM: C = (A(MxK) * W(KxN) + bias)*oscale ----------------
// MODE 0: row-major bf16 out (optional relu)   [FFN1, final o1]
// MODE 1: Q/K scatter to (b,h,l,32) bf16
// MODE 2: V scatter to (b,h,32,l) bf16 (transposed for PV B-fragments)
// MODE 3: fp32 out = acc + bias + res (residual), N==256
template<int MODE, int RELU>
__global__ __launch_bounds__(256) void k_gemm(
    const unsigned short* __restrict__ A, const unsigned short* __restrict__ W,
    const float* __restrict__ bias, const float* __restrict__ res,
    void* __restrict__ outp, float oscale, int M, int N, int K)
{
  __shared__ unsigned short As[64 * 40];  // (m,k) pitch 40
  __shared__ unsigned short Ws[64 * 40];  // transposed (n,k) pitch 40
  const int t = threadIdx.x;
  const int lane = t & 63, w = t >> 6;
  const int bm = blockIdx.y << 6, bn = blockIdx.x << 6;
  const int mw = (w & 1) << 5, nw = (w >> 1) << 5;
  const int q = lane >> 4, r = lane & 15;
  const int am = t >> 2, akc = (t & 3) << 3;   // A staging: row, col-chunk
  const int wk = t >> 3, wnc = (t & 7) << 3;   // W staging: k-row, n-chunk

  f32x4 zero = {0.f, 0.f, 0.f, 0.f};
  f32x4 acc[2][2] = {{zero, zero}, {zero, zero}};

  // register prefetch of first tile
  uint4 av = *(const uint4*)(A + (size_t)(bm + am) * K + akc);
  union { uint4 u; unsigned short s[8]; } wv;
  wv.u = *(const uint4*)(W + (size_t)wk * N + bn + wnc);

  for (int k0 = 0; k0 < K; k0 += 32) {
    *(uint4*)(As + am * 40 + akc) = av;
    #pragma unroll
    for (int j = 0; j < 8; ++j) Ws[(wnc + j) * 40 + wk] = wv.s[j];
    __syncthreads();

    if (k0 + 32 < K) {   // issue next-tile loads; latency hides under MFMAs
      av = *(const uint4*)(A + (size_t)(bm + am) * K + k0 + 32 + akc);
      wv.u = *(const uint4*)(W + (size_t)(k0 + 32 + wk) * N + bn + wnc);
    }

    bh8 a0 = *(const bh8*)(As + (mw + r) * 40 + (q << 3));
    bh8 a1 = *(const bh8*)(As + (mw + 16 + r) * 40 + (q << 3));
    bh8 b0 = *(const bh8*)(Ws + (nw + r) * 40 + (q << 3));
    bh8 b1 = *(const bh8*)(Ws + (nw + 16 + r) * 40 + (q << 3));
    acc[0][0] = __builtin_amdgcn_mfma_f32_16x16x32_bf16(a0, b0, acc[0][0], 0, 0, 0);
    acc[0][1] = __builtin_amdgcn_mfma_f32_16x16x32_bf16(a0, b1, acc[0][1], 0, 0, 0);
    acc[1][0] = __builtin_amdgcn_mfma_f32_16x16x32_bf16(a1, b0, acc[1][0], 0, 0, 0);
    acc[1][1] = __builtin_amdgcn_mfma_f32_16x16x32_bf16(a1, b1, acc[1][1], 0, 0, 0);
    __syncthreads();
  }

  #pragma unroll
  for (int mi = 0; mi < 2; ++mi)
  #pragma unroll
  for (int ni = 0; ni < 2; ++ni)
  #pragma unroll
  for (int rr = 0; rr < 4; ++rr) {
    int gm = bm + mw + (mi << 4) + (q << 2) + rr;   // C row = quad*4+reg
    int gn = bn + nw + (ni << 4) + r;               // C col = lane&15
    float v = (acc[mi][ni][rr] + bias[gn]) * oscale;
    if (RELU) v = v > 0.f ? v : 0.f;
    if (MODE == 0) {
      ((unsigned short*)outp)[(size_t)gm * N + gn] = f2b(v);
    } else if (MODE == 1) {
      int b = gm / LSEQ, l = gm - b * LSEQ;
      int hh = gn >> 5, e = gn & 31;
      ((unsigned short*)outp)[((((size_t)b * NH + hh) * LSEQ + l) << 5) + e] = f2b(v);
    } else if (MODE == 2) {
      int b = gm / LSEQ, l = gm - b * LSEQ;
      int hh = gn >> 5, e = gn & 31;
      ((unsigned short*)outp)[(((size_t)b * NH + hh) * 32 + e) * LSEQ + l] = f2b(v);
    } else {
      size_t idx = (size_t)gm * DM + gn;
      ((float*)outp)[idx] = v + res[idx];
    }
  }
}

// ---------------- residual LayerNorm: wave per row of 256 ----------------
__global__ __launch_bounds__(256) void k_ln(const float* __restrict__ y,
    const float* __restrict__ g, const float* __restrict__ bta,
    float* __restrict__ h, unsigned short* __restrict__ hb)
{
  int t = threadIdx.x, lane = t & 63, w = t >> 6;
  int row = blockIdx.x * 4 + w;
  const float* yr = y + (size_t)row * DM;
  float4 v = *(const float4*)(yr + lane * 4);
  float s = v.x + v.y + v.z + v.w;
  float sq = v.x * v.x + v.y * v.y + v.z * v.z + v.w * v.w;
  #pragma unroll
  for (int m = 1; m < 64; m <<= 1) { s += __shfl_xor(s, m, 64); sq += __shfl_xor(sq, m, 64); }
  float mean = s * (1.f / 256.f);
  float var = sq * (1.f / 256.f) - mean * mean;
  float rs = rsqrtf(var + 1e-5f);
  float4 gg = *(const float4*)(g + lane * 4);
  float4 bb = *(const float4*)(bta + lane * 4);
  float4 o;
  o.x = (v.x - mean) * rs * gg.x + bb.x;
  o.y = (v.y - mean) * rs * gg.y + bb.y;
  o.z = (v.z - mean) * rs * gg.z + bb.z;
  o.w = (v.w - mean) * rs * gg.w + bb.w;
  *(float4*)(h + (size_t)row * DM + lane * 4) = o;
  ushort4 u;
  u.x = f2b(o.x); u.y = f2b(o.y); u.z = f2b(o.z); u.w = f2b(o.w);
  *(ushort4*)(hb + (size_t)row * DM + lane * 4) = u;
}

// ---------------- fused attention: QK^T -> softmax -> P write -> PV ----------------
// block = (b, h, 16 Q-rows); 256 threads (4 waves); S bf16 in LDS (16 x SP)
// Q is pre-scaled by SCL (folded into projection). Phase 1 computes mfma(K,Q)
// so each lane holds 4 CONSECUTIVE k-columns of one q-row -> pack 2x cvt_pk
// -> single ds_write_b64 (replaces 4 f2b + 4 scalar ds_write_u16).
__global__ __launch_bounds__(256) void k_attn(
    const unsigned short* __restrict__ Qb, const unsigned short* __restrict__ Kb,
    const unsigned short* __restrict__ Vt, float* __restrict__ Pout,
    unsigned short* __restrict__ ao)
{
  __shared__ unsigned short S[16 * SP];
  __shared__ float red[4 * 16 * 32];
  __shared__ float rinv[16];
  const int t = threadIdx.x, lane = t & 63, w = t >> 6;
  const int bid = blockIdx.x;
  const int rb = bid % 126, bh = bid / 126;   // bh = b*NH + h
  const int l0 = rb << 4;
  const int q = lane >> 4, r = lane & 15;

  // phase 1: S[qrow][kcol] = Q K^T (already scaled), bf16 into LDS
  bh8 qf = *(const bh8*)(Qb + (((size_t)bh * LSEQ + l0 + r) << 5) + (q << 3));
  {
    const unsigned short* kb = Kb + (((size_t)bh * LSEQ) << 5) + (q << 3);
    unsigned short* srow = S + r * SP;
    int stb = w << 5;                       // contiguous per-wave strip ranges
    int ste = (w == 3) ? 126 : stb + 32;    // 32,32,32,30 -> all even counts
    for (int st = stb; st < ste; st += 2) { // paired: 2 K-loads in flight
      int s0 = st << 4, s1 = s0 + 16;
      bh8 kf0 = *(const bh8*)(kb + ((size_t)(s0 + r) << 5));
      bh8 kf1 = *(const bh8*)(kb + ((size_t)(s1 + r) << 5));
      f32x4 c0 = {0.f,0.f,0.f,0.f}, c1 = {0.f,0.f,0.f,0.f};
      c0 = __builtin_amdgcn_mfma_f32_16x16x32_bf16(kf0, qf, c0, 0, 0, 0);
      c1 = __builtin_amdgcn_mfma_f32_16x16x32_bf16(kf1, qf, c1, 0, 0, 0);
      uint2 u0, u1;
      u0.x = pk_bf16(c0[0], c0[1]); u0.y = pk_bf16(c0[2], c0[3]);
      u1.x = pk_bf16(c1[0], c1[1]); u1.y = pk_bf16(c1[2], c1[3]);
      *(uint2*)(srow + s0 + (q << 2)) = u0;   // cols s0+4q..s0+4q+3 of row r
      *(uint2*)(srow + s1 + (q << 2)) = u1;
    }
  }
  // pad cols [2016,2048) with most-negative-finite bf16 -> exp()=0, max-neutral
  *(unsigned int*)(S + (t >> 4) * SP + 2016 + ((t & 15) << 1)) = 0xFF7FFF7Fu;
  __syncthreads();

  // phase 2: per-row max & sum of exp; store unnormalized e back to LDS.
  // 8-wide vector LDS ops, uniform 16 iterations (2048 cols incl. pad).
  {
    int row = t >> 4, c = t & 15;   // 16 threads per row, same 16-lane group
    unsigned short* sr = S + row * SP;
    float mx = -1e30f;
    #pragma unroll 4
    for (int i = 0; i < 16; ++i) {
      bh8 v = *(const bh8*)(sr + ((c + (i << 4)) << 3));
      float m0 = fmaxf(fmaxf(b2f(v[0]), b2f(v[1])), fmaxf(b2f(v[2]), b2f(v[3])));
      float m1 = fmaxf(fmaxf(b2f(v[4]), b2f(v[5])), fmaxf(b2f(v[6]), b2f(v[7])));
      mx = fmaxf(mx, fmaxf(m0, m1));
    }
    #pragma unroll
    for (int m = 1; m < 16; m <<= 1) mx = fmaxf(mx, __shfl_xor(mx, m, 64));
    float sum = 0.f;
    #pragma unroll 4
    for (int i = 0; i < 16; ++i) {
      unsigned short* sp = sr + ((c + (i << 4)) << 3);
      bh8 v = *(const bh8*)sp;
      float e0 = __expf(b2f(v[0]) - mx), e1 = __expf(b2f(v[1]) - mx);
      float e2 = __expf(b2f(v[2]) - mx), e3 = __expf(b2f(v[3]) - mx);
      float e4 = __expf(b2f(v[4]) - mx), e5 = __expf(b2f(v[5]) - mx);
      float e6 = __expf(b2f(v[6]) - mx), e7 = __expf(b2f(v[7]) - mx);
      sum += ((e0 + e1) + (e2 + e3)) + ((e4 + e5) + (e6 + e7));
      uint4 pk;
      pk.x = pk_bf16(e0, e1); pk.y = pk_bf16(e2, e3);
      pk.z = pk_bf16(e4, e5); pk.w = pk_bf16(e6, e7);
      *(uint4*)sp = pk;
    }
    #pragma unroll
    for (int m = 1; m < 16; m <<= 1) sum += __shfl_xor(sum, m, 64);
    if (c == 0) rinv[row] = 1.f / sum;
  }
  __syncthreads();

  // phase 3: coalesced fp32 P write, 8 cols/thread (b128 LDS read + 2x float4 store)
  {
    float* prow0 = Pout + (size_t)bh * LSEQ * LSEQ + (size_t)l0 * LSEQ;
    if (t < 252) {
      for (int row = 0; row < 16; ++row) {
        float iv = rinv[row];
        bh8 v = *(const bh8*)(S + row * SP + (t << 3));
        float4 o0, o1;
        o0.x = b2f(v[0]) * iv; o0.y = b2f(v[1]) * iv;
        o0.z = b2f(v[2]) * iv; o0.w = b2f(v[3]) * iv;
        o1.x = b2f(v[4]) * iv; o1.y = b2f(v[5]) * iv;
        o1.z = b2f(v[6]) * iv; o1.w = b2f(v[7]) * iv;
        float* pr = prow0 + (size_t)row * LSEQ + (t << 3);
        *(float4*)pr = o0;
        *(float4*)(pr + 4) = o1;
      }
    }
  }

  // phase 4: O = (e @ V) * rinv via MFMA; A = e from LDS, B = Vt (b,h,d,s)
  f32x4 o0 = {0.f, 0.f, 0.f, 0.f}, o1 = {0.f, 0.f, 0.f, 0.f};
  {
    const unsigned short* vtb = Vt + (size_t)bh * 32 * LSEQ + (q << 3);
    const unsigned short* srow = S + r * SP + (q << 3);
    int pb = w << 4;                        // contiguous: 16,16,16,15 strips
    int pe = (w == 3) ? 63 : pb + 16;
    for (int st = pb; st + 1 < pe; st += 2) {
      int s0 = st << 5, s1 = s0 + 32;
      bh8 pf0 = *(const bh8*)(srow + s0);
      bh8 pf1 = *(const bh8*)(srow + s1);
      bh8 va0 = *(const bh8*)(vtb + (size_t)r * LSEQ + s0);
      bh8 vb0 = *(const bh8*)(vtb + (size_t)(16 + r) * LSEQ + s0);
      bh8 va1 = *(const bh8*)(vtb + (size_t)r * LSEQ + s1);
      bh8 vb1 = *(const bh8*)(vtb + (size_t)(16 + r) * LSEQ + s1);
      o0 = __builtin_amdgcn_mfma_f32_16x16x32_bf16(pf0, va0, o0, 0, 0, 0);
      o1 = __builtin_amdgcn_mfma_f32_16x16x32_bf16(pf0, vb0, o1, 0, 0, 0);
      o0 = __builtin_amdgcn_mfma_f32_16x16x32_bf16(pf1, va1, o0, 0, 0, 0);
      o1 = __builtin_amdgcn_mfma_f32_16x16x32_bf16(pf1, vb1, o1, 0, 0, 0);
    }
    if ((pe - pb) & 1) {                    // wave 3 tail strip
      int s0 = (pe - 1) << 5;
      bh8 pf = *(const bh8*)(srow + s0);
      bh8 va = *(const bh8*)(vtb + (size_t)r * LSEQ + s0);
      bh8 vb = *(const bh8*)(vtb + (size_t)(16 + r) * LSEQ + s0);
      o0 = __builtin_amdgcn_mfma_f32_16x16x32_bf16(pf, va, o0, 0, 0, 0);
      o1 = __builtin_amdgcn_mfma_f32_16x16x32_bf16(pf, vb, o1, 0, 0, 0);
    }
  }
  float* rw = red + w * 512;
  #pragma unroll
  for (int rr = 0; rr < 4; ++rr) {
    rw[(q * 4 + rr) * 32 + r] = o0[rr];
    rw[(q * 4 + rr) * 32 + 16 + r] = o1[rr];
  }
  __syncthreads();
  for (int idx = t; idx < 512; idx += 256) {
    int row = idx >> 5, d = idx & 31;
    float v = red[idx] + red[512 + idx] + red[1024 + idx] + red[1536 + idx];
    v *= rinv[row];
    int b = bh >> 2, hh = bh & 3;
    ao[(size_t)(b * LSEQ + l0 + row) * 128 + (hh << 5) + d] = f2b(v);
  }
}

// ---------------- final head: out = t1 @ o2w + o2b  (N=2) ----------------
__global__ __launch_bounds__(256) void k_head(const unsigned short* __restrict__ t1,
    const float* __restrict__ o2w, const float* __restrict__ o2b,
    float* __restrict__ outp)
{
  int t = threadIdx.x, lane = t & 63, w = t >> 6;
  int row = blockIdx.x * 4 + w;
  union { ushort4 u; unsigned short s[4]; } pk;
  pk.u = *(const ushort4*)(t1 + (size_t)row * DM + lane * 4);
  float a0 = 0.f, a1 = 0.f;
  #pragma unroll
  for (int j = 0; j < 4; ++j) {
    float xv = b2f(pk.s[j]);
    int k = lane * 4 + j;
    a0 += xv * o2w[k * 2];
    a1 += xv * o2w[k * 2 + 1];
  }
  #pragma unroll
  for (int m = 1; m < 64; m <<= 1) { a0 += __shfl_xor(a0, m, 64); a1 += __shfl_xor(a1, m, 64); }
  if (lane == 0) {
    outp[(size_t)row * 2]     = a0 + o2b[0];
    outp[(size_t)row * 2 + 1] = a1 + o2b[1];
  }
}

extern "C" void kernel_launch(void* const* d_in, const int* in_sizes, int n_in,
                              void* d_out, int out_size, void* d_ws, size_t ws_size,
                              hipStream_t stream) {
  const float* x    = (const float*)d_in[0];
  const float* in_w = (const float*)d_in[1];
  const float* in_b = (const float*)d_in[2];
  const float* qw   = (const float*)d_in[3];
  const float* qb   = (const float*)d_in[4];
  const float* kw   = (const float*)d_in[5];
  const float* kb   = (const float*)d_in[6];
  const float* vw   = (const float*)d_in[7];
  const float* vb   = (const float*)d_in[8];
  const float* ow   = (const float*)d_in[9];
  const float* ob   = (const float*)d_in[10];
  const float* f1w  = (const float*)d_in[11];
  const float* f1b  = (const float*)d_in[12];
  const float* f2w  = (const float*)d_in[13];
  const float* f2b  = (const float*)d_in[14];
  const float* n1g  = (const float*)d_in[15];
  const float* n1b  = (const float*)d_in[16];
  const float* n2g  = (const float*)d_in[17];
  const float* n2b  = (const float*)d_in[18];
  const float* o1w  = (const float*)d_in[19];
  const float* o1b  = (const float*)d_in[20];
  const float* o2w  = (const float*)d_in[21];
  const float* o2b  = (const float*)d_in[22];

  char* p = (char*)d_ws;
  auto alloc = [&](size_t bytes) { char* r = p; p += (bytes + 255) & ~(size_t)255; return r; };
  float*          h    = (float*)alloc((size_t)MR * DM * 4);
  unsigned short* hb   = (unsigned short*)alloc((size_t)MR * DM * 2);
  float*          tmp  = (float*)alloc((size_t)MR * DM * 4);
  unsigned short* Qb   = (unsigned short*)alloc((size_t)MR * 128 * 2);
  unsigned short* Kb   = (unsigned short*)alloc((size_t)MR * 128 * 2);
  unsigned short* Vt   = (unsigned short*)alloc((size_t)MR * 128 * 2);
  unsigned short* ao   = (unsigned short*)alloc((size_t)MR * 128 * 2);
  unsigned short* Fb   = (unsigned short*)alloc((size_t)MR * FCN * 2);
  unsigned short* t1   = (unsigned short*)alloc((size_t)MR * DM * 2);
  unsigned short* qwb  = (unsigned short*)alloc(98304 * 2);
  unsigned short* kwb  = (unsigned short*)alloc(98304 * 2);
  unsigned short* vwb  = (unsigned short*)alloc(98304 * 2);
  unsigned short* owb  = (unsigned short*)alloc(98304 * 2);
  unsigned short* f1wb = (unsigned short*)alloc(49152 * 2);
  unsigned short* f2wb = (unsigned short*)alloc(49152 * 2);
  unsigned short* o1wb = (unsigned short*)alloc(65536 * 2);

  k_f2bf<<<(98304 + 255) / 256, 256, 0, stream>>>(qw, qwb, 98304);
  k_f2bf<<<(98304 + 255) / 256, 256, 0, stream>>>(kw, kwb, 98304);
  k_f2bf<<<(98304 + 255) / 256, 256, 0, stream>>>(vw, vwb, 98304);
  k_f2bf<<<(98304 + 255) / 256, 256, 0, stream>>>(ow, owb, 98304);
  k_f2bf<<<(49152 + 255) / 256, 256, 0, stream>>>(f1w, f1wb, 49152);
  k_f2bf<<<(49152 + 255) / 256, 256, 0, stream>>>(f2w, f2wb, 49152);
  k_f2bf<<<(65536 + 255) / 256, 256, 0, stream>>>(o1w, o1wb, 65536);

  k_embed<<<MR, 256, 0, stream>>>(x, in_w, in_b, h, hb);

  float* outp = (float*)d_out;
  for (int i = 0; i < NLAY; ++i) {
    k_gemm<1, 0><<<dim3(2, 252), 256, 0, stream>>>(hb, qwb + i * 32768, qb + i * 128, nullptr, Qb, SCL, MR, 128, 256);
    k_gemm<1, 0><<<dim3(2, 252), 256, 0, stream>>>(hb, kwb + i * 32768, kb + i * 128, nullptr, Kb, 1.f, MR, 128, 256);
    k_gemm<2, 0><<<dim3(2, 252), 256, 0, stream>>>(hb, vwb + i * 32768, vb + i * 128, nullptr, Vt, 1.f, MR, 128, 256);
    k_attn<<<4032, 256, 0, stream>>>(Qb, Kb, Vt,
        outp + 32256 + (size_t)i * NB * NH * LSEQ * LSEQ, ao);
    k_gemm<3, 0><<<dim3(4, 252), 256, 0, stream>>>(ao, owb + i * 32768, ob + i * 256, h, tmp, 1.f, MR, 256, 128);
    k_ln<<<MR / 4, 256, 0, stream>>>(tmp, n1g + i * 256, n1b + i * 256, h, hb);
    k_gemm<0, 1><<<dim3(1, 252), 256, 0, stream>>>(hb, f1wb + i * 16384, f1b + i * 64, nullptr, Fb, 1.f, MR, 64, 256);
    k_gemm<3, 0><<<dim3(4, 252), 256, 0, stream>>>(Fb, f2wb + i * 16384, f2b + i * 256, h, tmp, 1.f, MR, 256, 64);
    k_ln<<<MR / 4, 256, 0, stream>>>(tmp, n2g + i * 256, n2b + i * 256, h, hb);
  }
  k_gemm<0, 1><<<dim3(4, 252), 256, 0, stream>>>(hb, o1wb, o1b, nullptr, t1, 1.f, MR, 256, 256);
  k_head<<<MR / 4, 256, 0, stream>>>(t1, o2w, o2b, outp);
}

// Round 2
// 2129.144 us; speedup vs baseline: 1.2080x; 1.0047x over previous
//
#include <hip/hip_runtime.h>

typedef __attribute__((ext_vector_type(8))) short bh8;
typedef __attribute__((ext_vector_type(4))) float f32x4;

#define NB   8
#define NLAY 3
#define LSEQ 2016
#define NH   4
#define DM   256
#define FCN  64
#define MR   (NB*LSEQ)     /* 16128 */
#define SCL  0.0625f       /* 1/sqrt(D)=1/16 per module quirk; folded into Q projection */
#define TP   40            /* attn P-tile pitch in shorts (80 B rows: 16B-aligned, <=2-way banks) */

__device__ __forceinline__ float b2f(unsigned short u) {
  union { unsigned int i; float f; } c; c.i = ((unsigned int)u) << 16; return c.f;
}
__device__ __forceinline__ unsigned short f2b(float f) {
  union { float f; unsigned int i; } c; c.f = f;
  unsigned int r = c.i + 0x7fffu + ((c.i >> 16) & 1u);  // RNE
  return (unsigned short)(r >> 16);
}
__device__ __forceinline__ unsigned int pk_bf16(float lo, float hi) {
  unsigned int r;
  asm("v_cvt_pk_bf16_f32 %0, %1, %2" : "=v"(r) : "v"(lo), "v"(hi));
  return r;
}

// ---------------- fp32 -> bf16 weight conversion ----------------
__global__ __launch_bounds__(256) void k_f2bf(const float* __restrict__ s,
    unsigned short* __restrict__ d, int n) {
  int i = blockIdx.x * 256 + threadIdx.x;
  if (i < n) d[i] = f2b(s[i]);
}

// ---------------- input embedding: h = x @ in_w + in_b (K=2) ----------------
__global__ __launch_bounds__(256) void k_embed(const float* __restrict__ x,
    const float* __restrict__ w, const float* __restrict__ bias,
    float* __restrict__ h, unsigned short* __restrict__ hb) {
  int m = blockIdx.x, d = threadIdx.x;
  float v = x[m*2] * w[d] + x[m*2+1] * w[DM + d] + bias[d];
  size_t idx = (size_t)m * DM + d;
  h[idx] = v;
  hb[idx] = f2b(v);
}

// ---------------- generic bf16 MFMA GEMM: C = (A(MxK) * W(KxN) + bias)*oscale ----------------
// MODE 0: row-major bf16 out (optional relu)   [FFN1, final o1]
// MODE 1: Q/K scatter to (b,h,l,32) bf16
// MODE 2: V scatter to (b,h,32,l) bf16 (transposed for PV B-fragments)
// MODE 3: fp32 out = acc + bias + res (residual), N==256
template<int MODE, int RELU>
__global__ __launch_bounds__(256) void k_gemm(
    const unsigned short* __restrict__ A, const unsigned short* __restrict__ W,
    const float* __restrict__ bias, const float* __restrict__ res,
    void* __restrict__ outp, float oscale, int M, int N, int K)
{
  __shared__ unsigned short As[64 * 40];  // (m,k) pitch 40
  __shared__ unsigned short Ws[64 * 40];  // transposed (n,k) pitch 40
  const int t = threadIdx.x;
  const int lane = t & 63, w = t >> 6;
  const int bm = blockIdx.y << 6, bn = blockIdx.x << 6;
  const int mw = (w & 1) << 5, nw = (w >> 1) << 5;
  const int q = lane >> 4, r = lane & 15;
  const int am = t >> 2, akc = (t & 3) << 3;   // A staging: row, col-chunk
  const int wk = t >> 3, wnc = (t & 7) << 3;   // W staging: k-row, n-chunk

  f32x4 zero = {0.f, 0.f, 0.f, 0.f};
  f32x4 acc[2][2] = {{zero, zero}, {zero, zero}};

  // register prefetch of first tile
  uint4 av = *(const uint4*)(A + (size_t)(bm + am) * K + akc);
  union { uint4 u; unsigned short s[8]; } wv;
  wv.u = *(const uint4*)(W + (size_t)wk * N + bn + wnc);

  for (int k0 = 0; k0 < K; k0 += 32) {
    *(uint4*)(As + am * 40 + akc) = av;
    #pragma unroll
    for (int j = 0; j < 8; ++j) Ws[(wnc + j) * 40 + wk] = wv.s[j];
    __syncthreads();

    if (k0 + 32 < K) {   // issue next-tile loads; latency hides under MFMAs
      av = *(const uint4*)(A + (size_t)(bm + am) * K + k0 + 32 + akc);
      wv.u = *(const uint4*)(W + (size_t)(k0 + 32 + wk) * N + bn + wnc);
    }

    bh8 a0 = *(const bh8*)(As + (mw + r) * 40 + (q << 3));
    bh8 a1 = *(const bh8*)(As + (mw + 16 + r) * 40 + (q << 3));
    bh8 b0 = *(const bh8*)(Ws + (nw + r) * 40 + (q << 3));
    bh8 b1 = *(const bh8*)(Ws + (nw + 16 + r) * 40 + (q << 3));
    acc[0][0] = __builtin_amdgcn_mfma_f32_16x16x32_bf16(a0, b0, acc[0][0], 0, 0, 0);
    acc[0][1] = __builtin_amdgcn_mfma_f32_16x16x32_bf16(a0, b1, acc[0][1], 0, 0, 0);
    acc[1][0] = __builtin_amdgcn_mfma_f32_16x16x32_bf16(a1, b0, acc[1][0], 0, 0, 0);
    acc[1][1] = __builtin_amdgcn_mfma_f32_16x16x32_bf16(a1, b1, acc[1][1], 0, 0, 0);
    __syncthreads();
  }

  #pragma unroll
  for (int mi = 0; mi < 2; ++mi)
  #pragma unroll
  for (int ni = 0; ni < 2; ++ni)
  #pragma unroll
  for (int rr = 0; rr < 4; ++rr) {
    int gm = bm + mw + (mi << 4) + (q << 2) + rr;   // C row = quad*4+reg
    int gn = bn + nw + (ni << 4) + r;               // C col = lane&15
    float v = (acc[mi][ni][rr] + bias[gn]) * oscale;
    if (RELU) v = v > 0.f ? v : 0.f;
    if (MODE == 0) {
      ((unsigned short*)outp)[(size_t)gm * N + gn] = f2b(v);
    } else if (MODE == 1) {
      int b = gm / LSEQ, l = gm - b * LSEQ;
      int hh = gn >> 5, e = gn & 31;
      ((unsigned short*)outp)[((((size_t)b * NH + hh) * LSEQ + l) << 5) + e] = f2b(v);
    } else if (MODE == 2) {
      int b = gm / LSEQ, l = gm - b * LSEQ;
      int hh = gn >> 5, e = gn & 31;
      ((unsigned short*)outp)[(((size_t)b * NH + hh) * 32 + e) * LSEQ + l] = f2b(v);
    } else {
      size_t idx = (size_t)gm * DM + gn;
      ((float*)outp)[idx] = v + res[idx];
    }
  }
}

// ---------------- residual LayerNorm: wave per row of 256 ----------------
__global__ __launch_bounds__(256) void k_ln(const float* __restrict__ y,
    const float* __restrict__ g, const float* __restrict__ bta,
    float* __restrict__ h, unsigned short* __restrict__ hb)
{
  int t = threadIdx.x, lane = t & 63, w = t >> 6;
  int row = blockIdx.x * 4 + w;
  const float* yr = y + (size_t)row * DM;
  float4 v = *(const float4*)(yr + lane * 4);
  float s = v.x + v.y + v.z + v.w;
  float sq = v.x * v.x + v.y * v.y + v.z * v.z + v.w * v.w;
  #pragma unroll
  for (int m = 1; m < 64; m <<= 1) { s += __shfl_xor(s, m, 64); sq += __shfl_xor(sq, m, 64); }
  float mean = s * (1.f / 256.f);
  float var = sq * (1.f / 256.f) - mean * mean;
  float rs = rsqrtf(var + 1e-5f);
  float4 gg = *(const float4*)(g + lane * 4);
  float4 bb = *(const float4*)(bta + lane * 4);
  float4 o;
  o.x = (v.x - mean) * rs * gg.x + bb.x;
  o.y = (v.y - mean) * rs * gg.y + bb.y;
  o.z = (v.z - mean) * rs * gg.z + bb.z;
  o.w = (v.w - mean) * rs * gg.w + bb.w;
  *(float4*)(h + (size_t)row * DM + lane * 4) = o;
  ushort4 u;
  u.x = f2b(o.x); u.y = f2b(o.y); u.z = f2b(o.z); u.w = f2b(o.w);
  *(ushort4*)(hb + (size_t)row * DM + lane * 4) = u;
}

// ---------------- fused attention, flash-style two-pass ----------------
// block = (b, h, 16 Q-rows); 256 threads (4 waves).
// Pass 1: stream K, mfma(K,Q), per-lane online (max, sumexp). Tiny merge in LDS.
// Pass 2: recompute S, write normalized fp32 P straight to global (coalesced
// float4), pack e->bf16 through a wave-private double-buffered 1.25 KB LDS
// tile into the MFMA A-fragment layout, accumulate PV.
// Total LDS ~19 KB (was 74 KB) -> occupancy is VGPR-bound, latency hidden by TLP.
__global__ __launch_bounds__(256) void k_attn(
    const unsigned short* __restrict__ Qb, const unsigned short* __restrict__ Kb,
    const unsigned short* __restrict__ Vt, float* __restrict__ Pout,
    unsigned short* __restrict__ ao)
{
  __shared__ __align__(16) unsigned short tile[4][2][16 * TP];  // 10 KB
  __shared__ float mbuf[4][16][2];                              // 512 B
  __shared__ float rowstat[16][2];                              // 128 B  (m, rinv)
  __shared__ float red[4 * 512];                                // 8 KB
  const int t = threadIdx.x, lane = t & 63, w = t >> 6;
  const int bid = blockIdx.x;
  const int rb = bid % 126, bh = bid / 126;   // bh = b*NH + h
  const int l0 = rb << 4;
  const int q = lane >> 4, r = lane & 15;

  bh8 qf = *(const bh8*)(Qb + (((size_t)bh * LSEQ + l0 + r) << 5) + (q << 3));
  const unsigned short* kb = Kb + (((size_t)bh * LSEQ) << 5) + (q << 3);

  const int stb = w << 5;                     // strips [stb, ste): 32,32,32,30
  const int ste = (w == 3) ? 126 : stb + 32;

  // ---- pass 1: per-lane online (m, l) over this wave's strips ----
  float m = -1e30f, l = 0.f;
  for (int st = stb; st < ste; st += 2) {
    int kbase = st << 4;
    bh8 kf0 = *(const bh8*)(kb + ((size_t)(kbase + r) << 5));
    bh8 kf1 = *(const bh8*)(kb + ((size_t)(kbase + 16 + r) << 5));
    f32x4 z = {0.f, 0.f, 0.f, 0.f};
    f32x4 c0 = __builtin_amdgcn_mfma_f32_16x16x32_bf16(kf0, qf, z, 0, 0, 0);
    f32x4 c1 = __builtin_amdgcn_mfma_f32_16x16x32_bf16(kf1, qf, z, 0, 0, 0);
    float mx = fmaxf(fmaxf(fmaxf(c0[0], c0[1]), fmaxf(c0[2], c0[3])),
                     fmaxf(fmaxf(c1[0], c1[1]), fmaxf(c1[2], c1[3])));
    float mn = fmaxf(m, mx);
    float sc = __expf(m - mn);    // ==1 when max unchanged; ==0 from -1e30 init
    float s = ((__expf(c0[0]-mn) + __expf(c0[1]-mn)) + (__expf(c0[2]-mn) + __expf(c0[3]-mn)))
            + ((__expf(c1[0]-mn) + __expf(c1[1]-mn)) + (__expf(c1[2]-mn) + __expf(c1[3]-mn)));
    l = l * sc + s;
    m = mn;
  }
  // merge across the 4 q-groups (lanes r, r+16, r+32, r+48)
  #pragma unroll
  for (int mk = 16; mk < 64; mk <<= 1) {
    float mo = __shfl_xor(m, mk, 64);
    float lo = __shfl_xor(l, mk, 64);
    float mn = fmaxf(m, mo);
    l = l * __expf(m - mn) + lo * __expf(mo - mn);
    m = mn;
  }
  if (q == 0) { mbuf[w][r][0] = m; mbuf[w][r][1] = l; }
  __syncthreads();
  if (t < 16) {
    float mm = -1e30f, ll = 0.f;
    #pragma unroll
    for (int wv = 0; wv < 4; ++wv) {
      float m2 = mbuf[wv][t][0], l2 = mbuf[wv][t][1];
      float mn = fmaxf(mm, m2);
      ll = ll * __expf(mm - mn) + l2 * __expf(m2 - mn);
      mm = mn;
    }
    rowstat[t][0] = mm;
    rowstat[t][1] = 1.f / ll;
  }
  __syncthreads();
  const float mrow = rowstat[r][0];
  const float rinv = rowstat[r][1];

  // ---- pass 2: recompute, write P (fp32, normalized), accumulate PV ----
  f32x4 o0 = {0.f, 0.f, 0.f, 0.f}, o1 = {0.f, 0.f, 0.f, 0.f};
  const unsigned short* vtb = Vt + (size_t)bh * 32 * LSEQ;
  float* prow = Pout + (size_t)bh * LSEQ * LSEQ + (size_t)(l0 + r) * LSEQ + (q << 2);
  unsigned short* tA = &tile[w][0][0];
  unsigned short* tB = &tile[w][1][0];
  int pb = 0;
  for (int st = stb; st < ste; st += 2, pb ^= 1) {
    int kbase = st << 4;
    bh8 kf0 = *(const bh8*)(kb + ((size_t)(kbase + r) << 5));
    bh8 kf1 = *(const bh8*)(kb + ((size_t)(kbase + 16 + r) << 5));
    f32x4 z = {0.f, 0.f, 0.f, 0.f};
    f32x4 c0 = __builtin_amdgcn_mfma_f32_16x16x32_bf16(kf0, qf, z, 0, 0, 0);
    f32x4 c1 = __builtin_amdgcn_mfma_f32_16x16x32_bf16(kf1, qf, z, 0, 0, 0);
    float e0 = __expf(c0[0]-mrow), e1 = __expf(c0[1]-mrow);
    float e2 = __expf(c0[2]-mrow), e3 = __expf(c0[3]-mrow);
    float e4 = __expf(c1[0]-mrow), e5 = __expf(c1[1]-mrow);
    float e6 = __expf(c1[2]-mrow), e7 = __expf(c1[3]-mrow);
    float4 p0, p1;
    p0.x = e0*rinv; p0.y = e1*rinv; p0.z = e2*rinv; p0.w = e3*rinv;
    p1.x = e4*rinv; p1.y = e5*rinv; p1.z = e6*rinv; p1.w = e7*rinv;
    *(float4*)(prow + kbase) = p0;        // row l0+r, cols kbase+q*4.. (64B/row segs)
    *(float4*)(prow + kbase + 16) = p1;
    unsigned short* tp = pb ? tB : tA;
    uint2 u0, u1;
    u0.x = pk_bf16(e0, e1); u0.y = pk_bf16(e2, e3);
    u1.x = pk_bf16(e4, e5); u1.y = pk_bf16(e6, e7);
    __builtin_amdgcn_wave_barrier();      // WAR vs this tile's previous read
    *(uint2*)(tp + r * TP + (q << 2)) = u0;        // strip0: cols q*4..q*4+3
    *(uint2*)(tp + r * TP + 16 + (q << 2)) = u1;   // strip1: cols 16+q*4..
    __builtin_amdgcn_wave_barrier();      // RAW: cross-lane write -> read below
    bh8 pf = *(const bh8*)(tp + r * TP + (q << 3));
    bh8 va = *(const bh8*)(vtb + (size_t)r * LSEQ + kbase + (q << 3));
    bh8 vb = *(const bh8*)(vtb + (size_t)(16 + r) * LSEQ + kbase + (q << 3));
    o0 = __builtin_amdgcn_mfma_f32_16x16x32_bf16(pf, va, o0, 0, 0, 0);
    o1 = __builtin_amdgcn_mfma_f32_16x16x32_bf16(pf, vb, o1, 0, 0, 0);
  }

  // ---- cross-wave reduce of O and store ----
  float* rw = red + w * 512;
  #pragma unroll
  for (int rr = 0; rr < 4; ++rr) {
    rw[(q * 4 + rr) * 32 + r] = o0[rr];
    rw[(q * 4 + rr) * 32 + 16 + r] = o1[rr];
  }
  __syncthreads();
  for (int idx = t; idx < 512; idx += 256) {
    int row = idx >> 5, d = idx & 31;
    float v = red[idx] + red[512 + idx] + red[1024 + idx] + red[1536 + idx];
    v *= rowstat[row][1];
    int b = bh >> 2, hh = bh & 3;
    ao[(size_t)(b * LSEQ + l0 + row) * 128 + (hh << 5) + d] = f2b(v);
  }
}

// ---------------- final head: out = t1 @ o2w + o2b  (N=2) ----------------
__global__ __launch_bounds__(256) void k_head(const unsigned short* __restrict__ t1,
    const float* __restrict__ o2w, const float* __restrict__ o2b,
    float* __restrict__ outp)
{
  int t = threadIdx.x, lane = t & 63, w = t >> 6;
  int row = blockIdx.x * 4 + w;
  union { ushort4 u; unsigned short s[4]; } pk;
  pk.u = *(const ushort4*)(t1 + (size_t)row * DM + lane * 4);
  float a0 = 0.f, a1 = 0.f;
  #pragma unroll
  for (int j = 0; j < 4; ++j) {
    float xv = b2f(pk.s[j]);
    int k = lane * 4 + j;
    a0 += xv * o2w[k * 2];
    a1 += xv * o2w[k * 2 + 1];
  }
  #pragma unroll
  for (int m = 1; m < 64; m <<= 1) { a0 += __shfl_xor(a0, m, 64); a1 += __shfl_xor(a1, m, 64); }
  if (lane == 0) {
    outp[(size_t)row * 2]     = a0 + o2b[0];
    outp[(size_t)row * 2 + 1] = a1 + o2b[1];
  }
}

extern "C" void kernel_launch(void* const* d_in, const int* in_sizes, int n_in,
                              void* d_out, int out_size, void* d_ws, size_t ws_size,
                              hipStream_t stream) {
  const float* x    = (const float*)d_in[0];
  const float* in_w = (const float*)d_in[1];
  const float* in_b = (const float*)d_in[2];
  const float* qw   = (const float*)d_in[3];
  const float* qb   = (const float*)d_in[4];
  const float* kw   = (const float*)d_in[5];
  const float* kb   = (const float*)d_in[6];
  const float* vw   = (const float*)d_in[7];
  const float* vb   = (const float*)d_in[8];
  const float* ow   = (const float*)d_in[9];
  const float* ob   = (const float*)d_in[10];
  const float* f1w  = (const float*)d_in[11];
  const float* f1b  = (const float*)d_in[12];
  const float* f2w  = (const float*)d_in[13];
  const float* f2b  = (const float*)d_in[14];
  const float* n1g  = (const float*)d_in[15];
  const float* n1b  = (const float*)d_in[16];
  const float* n2g  = (const float*)d_in[17];
  const float* n2b  = (const float*)d_in[18];
  const float* o1w  = (const float*)d_in[19];
  const float* o1b  = (const float*)d_in[20];
  const float* o2w  = (const float*)d_in[21];
  const float* o2b  = (const float*)d_in[22];

  char* p = (char*)d_ws;
  auto alloc = [&](size_t bytes) { char* r = p; p += (bytes + 255) & ~(size_t)255; return r; };
  float*          h    = (float*)alloc((size_t)MR * DM * 4);
  unsigned short* hb   = (unsigned short*)alloc((size_t)MR * DM * 2);
  float*          tmp  = (float*)alloc((size_t)MR * DM * 4);
  unsigned short* Qb   = (unsigned short*)alloc((size_t)MR * 128 * 2);
  unsigned short* Kb   = (unsigned short*)alloc((size_t)MR * 128 * 2);
  unsigned short* Vt   = (unsigned short*)alloc((size_t)MR * 128 * 2);
  unsigned short* ao   = (unsigned short*)alloc((size_t)MR * 128 * 2);
  unsigned short* Fb   = (unsigned short*)alloc((size_t)MR * FCN * 2);
  unsigned short* t1   = (unsigned short*)alloc((size_t)MR * DM * 2);
  unsigned short* qwb  = (unsigned short*)alloc(98304 * 2);
  unsigned short* kwb  = (unsigned short*)alloc(98304 * 2);
  unsigned short* vwb  = (unsigned short*)alloc(98304 * 2);
  unsigned short* owb  = (unsigned short*)alloc(98304 * 2);
  unsigned short* f1wb = (unsigned short*)alloc(49152 * 2);
  unsigned short* f2wb = (unsigned short*)alloc(49152 * 2);
  unsigned short* o1wb = (unsigned short*)alloc(65536 * 2);

  k_f2bf<<<(98304 + 255) / 256, 256, 0, stream>>>(qw, qwb, 98304);
  k_f2bf<<<(98304 + 255) / 256, 256, 0, stream>>>(kw, kwb, 98304);
  k_f2bf<<<(98304 + 255) / 256, 256, 0, stream>>>(vw, vwb, 98304);
  k_f2bf<<<(98304 + 255) / 256, 256, 0, stream>>>(ow, owb, 98304);
  k_f2bf<<<(49152 + 255) / 256, 256, 0, stream>>>(f1w, f1wb, 49152);
  k_f2bf<<<(49152 + 255) / 256, 256, 0, stream>>>(f2w, f2wb, 49152);
  k_f2bf<<<(65536 + 255) / 256, 256, 0, stream>>>(o1w, o1wb, 65536);

  k_embed<<<MR, 256, 0, stream>>>(x, in_w, in_b, h, hb);

  float* outp = (float*)d_out;
  for (int i = 0; i < NLAY; ++i) {
    k_gemm<1, 0><<<dim3(2, 252), 256, 0, stream>>>(hb, qwb + i * 32768, qb + i * 128, nullptr, Qb, SCL, MR, 128, 256);
    k_gemm<1, 0><<<dim3(2, 252), 256, 0, stream>>>(hb, kwb + i * 32768, kb + i * 128, nullptr, Kb, 1.f, MR, 128, 256);
    k_gemm<2, 0><<<dim3(2, 252), 256, 0, stream>>>(hb, vwb + i * 32768, vb + i * 128, nullptr, Vt, 1.f, MR, 128, 256);
    k_attn<<<4032, 256, 0, stream>>>(Qb, Kb, Vt,
        outp + 32256 + (size_t)i * NB * NH * LSEQ * LSEQ, ao);
    k_gemm<3, 0><<<dim3(4, 252), 256, 0, stream>>>(ao, owb + i * 32768, ob + i * 256, h, tmp, 1.f, MR, 256, 128);
    k_ln<<<MR / 4, 256, 0, stream>>>(tmp, n1g + i * 256, n1b + i * 256, h, hb);
    k_gemm<0, 1><<<dim3(1, 252), 256, 0, stream>>>(hb, f1wb + i * 16384, f1b + i * 64, nullptr, Fb, 1.f, MR, 64, 256);
    k_gemm<3, 0><<<dim3(4, 252), 256, 0, stream>>>(Fb, f2wb + i * 16384, f2b + i * 256, h, tmp, 1.f, MR, 256, 64);
    k_ln<<<MR / 4, 256, 0, stream>>>(tmp, n2g + i * 256, n2b + i * 256, h, hb);
  }
  k_gemm<0, 1><<<dim3(4, 252), 256, 0, stream>>>(hb, o1wb, o1b, nullptr, t1, 1.f, MR, 256, 256);
  k_head<<<MR / 4, 256, 0, stream>>>(t1, o2w, o2b, outp);
}